// Round 1
// 139.735 us; speedup vs baseline: 1.0907x; 1.0907x over previous
//
#include <hip/hip_runtime.h>

// y:   (B=32, K=64, n1=4, n2=8, n3=8) fp32
// W1d: (K,1,256,1,1) -> w1[k][i]
// W2d: (K,1,1,4,4)   -> w2[k][j][l]
// out[b, x*256+i, yy*4+j, z*4+l] = sum_k y[b,k,x,yy,z] * w1[k,i] * w2[k,j,l]
//
// MFMA formulation (validated in earlier rounds at absmax 0.25):
//   per (b,x,yy): out[i,c] = sum_k w1[k,i] * s[k,c],
//   c = j*32 + z*4 + l in [0,128), s[k,c] = y[k,z]*w2[k,j,l], bf16 in / fp32 acc.
//
// Round-6 change: MERGE the iq split into one block. sT depends only on
// (b,x,yy) but was previously rebuilt by 4 blocks (iq=0..3) -> 4x redundant
// phase-B VALU + staging. Now: grid 1024 (b,x,yy), 512 threads (8 waves),
// each wave owns 2 i-tiles x 8 c-tiles (acc[2][8]).
// Phase B is vectorized: y and w2 staged TRANSPOSED ([z][k], [jl][k], rows
// padded to 68 floats for bank spread) so the s-build reads f32x4 from LDS
// instead of scalar LDS + scalar global.
//
// mfma_f32_16x16x32_bf16 layouts (m89/m91-verified):
//   A: lane holds A[m=lane&15][k=(lane>>4)*8 + j], j=0..7
//   B: lane holds B[k=(lane>>4)*8 + j][n=lane&15]
//   D: col=lane&15, row=(lane>>4)*4 + reg
// sT stored [c][k], k-stride padded to 72 ushorts (144 B): b128 frag reads are
// 16B-aligned, lanes la and la+8 alias exactly -> 2-way (free, m136).

typedef __bf16 bf16x8 __attribute__((ext_vector_type(8)));
typedef float  f32x4  __attribute__((ext_vector_type(4)));

#define LDK 72  // padded k-stride in ushorts for sT
#define YLD 68  // padded k-stride in floats for y_sT / w2T (68*4B = 17*16B)

__device__ __forceinline__ unsigned short f2bf(float f) {
    union { float f; unsigned u; } v; v.f = f;
    unsigned r = v.u + 0x7fffu + ((v.u >> 16) & 1u);   // round-to-nearest-even
    return (unsigned short)(r >> 16);
}
__device__ __forceinline__ unsigned pack2(float a, float b) {
    return (unsigned)f2bf(a) | ((unsigned)f2bf(b) << 16);
}

__global__ __launch_bounds__(512, 4)
void backproj_kernel(const float* __restrict__ y,
                     const float* __restrict__ w1,
                     const float* __restrict__ w2,
                     float* __restrict__ out)
{
    __shared__ float y_sT[8 * YLD];                        // ~2.1 KiB : y[z][k]
    __shared__ float w2T[16 * YLD];                        // ~4.3 KiB : w2[jl][k]
    __shared__ __align__(16) unsigned short sT[128 * LDK]; // 18 KiB   : [c][k] bf16

    const int bid = blockIdx.x;
    const int yy = bid & 7;
    const int x  = (bid >> 3) & 3;
    const int b  = bid >> 5;

    const int tid  = threadIdx.x;
    const int wv   = tid >> 6, lane = tid & 63;
    const int la   = lane & 15, quad = lane >> 4;

    // ---- issue staging loads (waves 0-1: y slice; waves 2-5: w2)
    float4 yv = {0.f, 0.f, 0.f, 0.f}, wvv = {0.f, 0.f, 0.f, 0.f};
    if (tid < 128) {
        const float* ybase = y + b * 16384 + x * 64 + yy * 8;
        int k = tid >> 1, h = tid & 1;
        yv = ((const float4*)(ybase + k * 256))[h];
    } else if (tid < 384) {
        int idx = tid - 128;
        int k = idx >> 2, g = idx & 3;
        wvv = ((const float4*)(w2 + k * 16))[g];
    }

    // ---- A-fragments straight from global w1 (64 KiB, L2-hot), overlap
    // with staging. a[it][h]: k = h*32 + quad*8 + j ; i = wv*32 + it*16 + la.
    bf16x8 a[2][2];
    #pragma unroll
    for (int it = 0; it < 2; ++it) {
        const float* wcol = w1 + wv * 32 + it * 16 + la;
        union { unsigned u[4]; bf16x8 v; } u0, u1;
        #pragma unroll
        for (int j2 = 0; j2 < 4; ++j2) {
            float f0 = wcol[(quad * 8 + 2 * j2) * 256];
            float f1 = wcol[(quad * 8 + 2 * j2 + 1) * 256];
            float g0 = wcol[(32 + quad * 8 + 2 * j2) * 256];
            float g1 = wcol[(32 + quad * 8 + 2 * j2 + 1) * 256];
            u0.u[j2] = pack2(f0, f1);
            u1.u[j2] = pack2(g0, g1);
        }
        a[it][0] = u0.v; a[it][1] = u1.v;
    }

    // ---- staging LDS writes (transposed layouts)
    if (tid < 128) {
        int k = tid >> 1, h = tid & 1;
        y_sT[(h * 4 + 0) * YLD + k] = yv.x;
        y_sT[(h * 4 + 1) * YLD + k] = yv.y;
        y_sT[(h * 4 + 2) * YLD + k] = yv.z;
        y_sT[(h * 4 + 3) * YLD + k] = yv.w;
    } else if (tid < 384) {
        int idx = tid - 128;
        int k = idx >> 2, g = idx & 3;
        w2T[(g * 4 + 0) * YLD + k] = wvv.x;
        w2T[(g * 4 + 1) * YLD + k] = wvv.y;
        w2T[(g * 4 + 2) * YLD + k] = wvv.z;
        w2T[(g * 4 + 3) * YLD + k] = wvv.w;
    }
    __syncthreads();   // y_sT, w2T ready

    // ---- phase B: sT[c][k] = bf16(y[k,z] * w2[k,jl]); 4 threads per c,
    // 16 k each, all reads are f32x4 from LDS.
    {
        const int c  = tid >> 2;             // 0..127
        const int kq = (tid & 3) * 16;       // k-quarter
        const int z  = (c >> 2) & 7;
        const int jl = (c >> 5) * 4 + (c & 3);   // j*4 + l
        const f32x4* yp = (const f32x4*)&y_sT[z * YLD + kq];
        const f32x4* wp = (const f32x4*)&w2T[jl * YLD + kq];
        unsigned* dst = (unsigned*)&sT[c * LDK + kq];
        #pragma unroll
        for (int q = 0; q < 4; ++q) {
            f32x4 a4 = yp[q], b4 = wp[q];
            dst[q * 2 + 0] = pack2(a4[0] * b4[0], a4[1] * b4[1]);
            dst[q * 2 + 1] = pack2(a4[2] * b4[2], a4[3] * b4[3]);
        }
    }
    __syncthreads();   // sT ready

    // ---- compute: per wave, 2 i-tiles x 8 c-tiles, K=64 (b-frags shared
    // across the 2 i-tiles)
    f32x4 acc[2][8];
    #pragma unroll
    for (int it = 0; it < 2; ++it)
        #pragma unroll
        for (int mt = 0; mt < 8; ++mt) acc[it][mt] = (f32x4){0.f, 0.f, 0.f, 0.f};

    #pragma unroll
    for (int mt = 0; mt < 8; ++mt) {
        const bf16x8 b0 = *(const bf16x8*)&sT[(mt * 16 + la) * LDK + quad * 8];
        const bf16x8 b1 = *(const bf16x8*)&sT[(mt * 16 + la) * LDK + 32 + quad * 8];
        acc[0][mt] = __builtin_amdgcn_mfma_f32_16x16x32_bf16(a[0][0], b0, acc[0][mt], 0, 0, 0);
        acc[0][mt] = __builtin_amdgcn_mfma_f32_16x16x32_bf16(a[0][1], b1, acc[0][mt], 0, 0, 0);
        acc[1][mt] = __builtin_amdgcn_mfma_f32_16x16x32_bf16(a[1][0], b0, acc[1][mt], 0, 0, 0);
        acc[1][mt] = __builtin_amdgcn_mfma_f32_16x16x32_bf16(a[1][1], b1, acc[1][mt], 0, 0, 0);
    }

    // ---- epilogue: D row=(quad*4+reg) -> i, col=la -> c (validated earlier)
    #pragma unroll
    for (int it = 0; it < 2; ++it) {
        const int i0 = wv * 32 + it * 16 + quad * 4;
        float* op = out + (size_t)(b * 1024 + x * 256 + i0) * 1024 + yy * 128 + la;
        #pragma unroll
        for (int mt = 0; mt < 8; ++mt) {
            float* o = op + mt * 16;
            o[0]    = acc[it][mt][0];
            o[1024] = acc[it][mt][1];
            o[2048] = acc[it][mt][2];
            o[3072] = acc[it][mt][3];
        }
    }
}

extern "C" void kernel_launch(void* const* d_in, const int* in_sizes, int n_in,
                              void* d_out, int out_size, void* d_ws, size_t ws_size,
                              hipStream_t stream) {
    const float* y  = (const float*)d_in[0];
    const float* w1 = (const float*)d_in[1];   // (64, 256)
    const float* w2 = (const float*)d_in[2];   // (64, 16)
    float* out = (float*)d_out;

    // grid = 32 b x 4 x x 8 yy = 1024 blocks of 512 threads
    backproj_kernel<<<dim3(1024), dim3(512), 0, stream>>>(y, w1, w2, out);
}